// Round 3
// baseline (4796.103 us; speedup 1.0000x reference)
//
#include <hip/hip_runtime.h>
#include <stdint.h>
#include <stddef.h>

// ---------------------------------------------------------------------------
// SNN policy forward, MI355X. B=2048, F=256, H=1024, O=256, T=64.
// 256 blocks = 16 groups (128 rows) x 16 h-slices (64 h). 4 waves: 2(M)x2(N).
// v_mfma_f32_32x32x16_f16, A = spikes {0,1} exact, B = f32 weights as hi+lo f16.
// Cross-block: bits ring via relaxed agent (sc1) atomics; relaxed group barrier.
// Readout computed block-locally (o-slice 16 cols, full K=1024, K-split by nj).
// ---------------------------------------------------------------------------

typedef _Float16 v8h  __attribute__((ext_vector_type(8)));
typedef float    v16f __attribute__((ext_vector_type(16)));

// workspace layout (bytes)
#define OFF_WSTM  0ull                 // main W tiles [hb16][c24][p2][64][72] f16 = 7,077,888
#define OFF_WSTO  7077888ull           // w_out tiles  [hb16][c16][p2][32][64] f16 = 2,097,152
#define OFF_BITS  9175040ull           // u32 ring [64][2048][48] = 25,165,824
#define OFF_CTR   34340864ull          // u32 [16][64] group barrier counters

#define SLOT_U32  (2048*48)

__device__ __forceinline__ float frn_add(float a, float b){ return __fadd_rn(a,b); }
__device__ __forceinline__ float frn_sub(float a, float b){ return __fsub_rn(a,b); }
__device__ __forceinline__ float frn_mul(float a, float b){ return __fmul_rn(a,b); }

// ---------------------------------------------------------------------------
// prep: tile/convert weights to hi/lo f16, zero bits slot 0 + counters
// ---------------------------------------------------------------------------
__global__ void k_prep(const float* __restrict__ w_in, const float* __restrict__ w_rec,
                       const float* __restrict__ w_out, uint8_t* __restrict__ ws)
{
    const long long stride = (long long)gridDim.x * blockDim.x;
    const long long id = (long long)blockIdx.x * blockDim.x + threadIdx.x;

    _Float16* wm = (_Float16*)(ws + OFF_WSTM);
    for (long long i = id; i < 16LL*24*2*64*72; i += stride) {
        int kk = (int)(i % 72); long long t2 = i / 72;
        int hrow = (int)(t2 % 64); t2 /= 64;
        int p = (int)(t2 % 2);  t2 /= 2;
        int c = (int)(t2 % 24); int hb = (int)(t2 / 24);
        _Float16 val = (_Float16)0.0f;
        if (kk < 64) {
            int h = hb*64 + hrow; int k = c*64 + kk;
            float wv = (k < 512) ? w_in[(size_t)h*512 + k] : w_rec[(size_t)h*1024 + (k - 512)];
            _Float16 hi = (_Float16)wv;
            val = p ? (_Float16)(wv - (float)hi) : hi;
        }
        wm[i] = val;
    }

    // w_out tiles: [(hb*16+c)*2+p][n32][k64], o = hb*16+n (n<16 real, else 0), h = c*64+k
    _Float16* wo = (_Float16*)(ws + OFF_WSTO);
    for (long long i = id; i < 16LL*16*2*32*64; i += stride) {
        int k = (int)(i % 64); long long t2 = i / 64;
        int n = (int)(t2 % 32); t2 /= 32;
        int p = (int)(t2 % 2); t2 /= 2;
        int c = (int)(t2 % 16); int hb = (int)(t2 / 16);
        _Float16 val = (_Float16)0.0f;
        if (n < 16) {
            float wv = w_out[(size_t)(hb*16 + n)*1024 + c*64 + k];
            _Float16 hi = (_Float16)wv;
            val = p ? (_Float16)(wv - (float)hi) : hi;
        }
        wo[i] = val;
    }

    uint32_t* bz = (uint32_t*)(ws + OFF_BITS);
    for (long long i = id; i < SLOT_U32; i += stride) bz[i] = 0u;   // slot 0: z(-1)=0
    uint32_t* ctr = (uint32_t*)(ws + OFF_CTR);
    for (long long i = id; i < 16*64; i += stride) ctr[i] = 0u;
}

// ---------------------------------------------------------------------------
// main persistent kernel
// ---------------------------------------------------------------------------
__global__ __launch_bounds__(256, 1)
void k_snn(const float* __restrict__ x, uint8_t* __restrict__ ws,
           float* __restrict__ outm, const int* __restrict__ seqp)
{
    extern __shared__ uint8_t smem[];
    // [0, 36864): B stage, 2 slots x [p2][64][72] f16
    // [36864, 61952): bits LDS [128][49] u32 (25088 B); aliased by X exchange [4][16][64] f32

    const int tid  = threadIdx.x;
    const int lane = tid & 63;
    const int wv4  = tid >> 6;
    const int mi   = wv4 >> 1;        // M half (64 rows)
    const int nj   = wv4 & 1;         // N half (32 h) + readout K-half
    const int q    = lane >> 5;
    const int ln   = lane & 31;

    const int b  = blockIdx.x;
    const int bb = b >> 4;                                 // group / batch tile
    const int hb = ((b & 7) << 1) | ((b >> 3) & 1);        // h-slice, XCD-local pairs
    const int rowBase = bb * 128;

    int T = *seqp; if (T > 64) T = 64; if (T < 1) T = 1;

    // readout state: own Mt = nj tile (rows mi*64+nj*32..+32, col hb*16+ln for ln<16)
    float io16[16], vo16[16], mx16[16];
#pragma unroll
    for (int i = 0; i < 16; ++i) { io16[i] = 0.f; vo16[i] = 0.f; mx16[i] = 0.f; }

    v16f zv;
#pragma unroll
    for (int k = 0; k < 16; ++k) zv[k] = 0.f;
    v16f vS[2], iS[2];
    vS[0] = zv; vS[1] = zv; iS[0] = zv; iS[1] = zv;

    // encoder state (threads 0..127 own one row x 32 features)
    float ve[32], cc[32];
    if (tid < 128) {
        const float* xr = x + (size_t)(rowBase + tid) * 256;
        const int f0 = (hb & 7) * 32;
        const float sgn = (hb < 8) ? 50.0f : -50.0f;
#pragma unroll
        for (int f = 0; f < 32; ++f) {
            float cv = frn_mul(sgn, xr[f0 + f]);
            cc[f] = fmaxf(cv, 0.0f);
            ve[f] = 0.0f;
        }
    }

    uint32_t* const bitsRing = (uint32_t*)(ws + OFF_BITS);
    uint32_t* const bitsL = (uint32_t*)(smem + 36864);
    uint32_t* const ctr = (uint32_t*)(ws + OFF_CTR) + bb * 64;
    const uint4* const wstg = (const uint4*)(ws + OFF_WSTM) + (size_t)(hb * 24) * 1152;
    const _Float16* const wouts = (const _Float16*)(ws + OFF_WSTO);
    uint4* const Bs = (uint4*)smem;

    auto enc_step = [&](int dstSlot) {
        if (tid < 128) {
            uint32_t wd = 0;
#pragma unroll
            for (int f = 0; f < 32; ++f) {
                float vv = ve[f];
                vv = frn_add(vv, frn_mul(0.1f, frn_add(frn_sub(0.0f, vv), cc[f])));
                bool zz = frn_sub(vv, 1.0f) > 0.0f;
                ve[f] = zz ? 0.0f : vv;
                wd |= zz ? (1u << f) : 0u;
            }
            __hip_atomic_store(&bitsRing[(size_t)dstSlot * SLOT_U32 + (size_t)(rowBase + tid) * 48 + hb],
                               wd, __ATOMIC_RELAXED, __HIP_MEMORY_SCOPE_AGENT);
        }
    };

    // relaxed group barrier: per-wave vmcnt drain (sc1 stores are then at the
    // coherence point) + relaxed agent-scope counter. NO release -> no buffer_wbl2.
    auto gbar = [&](int phase) {
        asm volatile("s_waitcnt vmcnt(0)" ::: "memory");
        __syncthreads();
        if (tid == 0) {
            __hip_atomic_fetch_add(ctr, 1u, __ATOMIC_RELAXED, __HIP_MEMORY_SCOPE_AGENT);
            const uint32_t tgt = 16u * (uint32_t)(phase + 1);
            while (__hip_atomic_load(ctr, __ATOMIC_RELAXED, __HIP_MEMORY_SCOPE_AGENT) < tgt)
                __builtin_amdgcn_s_sleep(1);
            asm volatile("" ::: "memory");
        }
        __syncthreads();
    };

    enc_step(0);   // xt(0) -> slot 0

    // preload chunk-0 weight tile for step 0
    uint4 pf[5];
    const int npf = (tid < 128) ? 5 : 4;
#pragma unroll
    for (int k2 = 0; k2 < 5; ++k2) if (k2 < npf) pf[k2] = wstg[tid + k2 * 256];

    for (int t = 0; t < T; ++t) {
        gbar(t);

        // ---- bits slot t -> LDS (sc1 loads, batched for MLP) ----
        {
            const uint32_t* bsrc = bitsRing + (size_t)t * SLOT_U32 + (size_t)rowBase * 48;
            uint32_t bw[12];
#pragma unroll
            for (int half = 0; half < 2; ++half) {
#pragma unroll
                for (int i2 = 0; i2 < 12; ++i2)
                    bw[i2] = __hip_atomic_load(bsrc + tid + (half * 12 + i2) * 256,
                                               __ATOMIC_RELAXED, __HIP_MEMORY_SCOPE_AGENT);
#pragma unroll
                for (int i2 = 0; i2 < 12; ++i2) {
                    int idx = tid + (half * 12 + i2) * 256;
                    int r = idx / 48, wq = idx - r * 48;
                    bitsL[r * 49 + wq] = bw[i2];
                }
            }
        }
        // ---- stage chunk 0 (preloaded) ----
#pragma unroll
        for (int k2 = 0; k2 < 5; ++k2) if (k2 < npf) Bs[tid + k2 * 256] = pf[k2];
        __syncthreads();

        v16f acc[2], oacc[2];
        acc[0] = zv; acc[1] = zv; oacc[0] = zv; oacc[1] = zv;

        for (int c = 0; c < 24; ++c) {
            if (c < 23) {
                const uint4* g = wstg + (size_t)(c + 1) * 1152;
#pragma unroll
                for (int k2 = 0; k2 < 5; ++k2) if (k2 < npf) pf[k2] = g[tid + k2 * 256];
            }
            const int cz = c - 8;
            const bool odut = ((unsigned)(cz - nj * 8) < 8u);   // this wave's readout K-duty
            uint4 wof[8];
            if (odut) {
                const _Float16* wob = wouts + ((size_t)(hb * 16 + cz) * 2) * 2048;
#pragma unroll
                for (int kc = 0; kc < 4; ++kc)
#pragma unroll
                    for (int p = 0; p < 2; ++p)
                        wof[kc * 2 + p] = *(const uint4*)(wob + (size_t)p * 2048 + ln * 64 + kc * 16 + q * 8);
            }

            const _Float16* Bt = (const _Float16*)(smem + (c & 1) * 18432);
            uint32_t wb[2];
#pragma unroll
            for (int kc = 0; kc < 4; ++kc) {
                if ((kc & 1) == 0) {
#pragma unroll
                    for (int Mt = 0; Mt < 2; ++Mt)
                        wb[Mt] = bitsL[(mi * 64 + Mt * 32 + ln) * 49 + (c * 2 + (kc >> 1))];
                }
                v8h A[2];
#pragma unroll
                for (int Mt = 0; Mt < 2; ++Mt) {
                    const uint32_t wv2 = wb[Mt];
                    const int sh = ((kc & 1) << 4) + (q << 3);
                    union { uint32_t u[4]; v8h h; } ua;
#pragma unroll
                    for (int j2 = 0; j2 < 4; ++j2) {
                        uint32_t pr = (wv2 >> (sh + 2 * j2)) & 3u;
                        uint32_t lo_ = (pr & 1u) ? 0x00003C00u : 0u;
                        uint32_t hi_ = (pr & 2u) ? 0x3C000000u : 0u;
                        ua.u[j2] = lo_ | hi_;
                    }
                    A[Mt] = ua.h;
                }
                const _Float16* brow = Bt + (size_t)(nj * 32 + ln) * 72 + kc * 16 + q * 8;
                v8h Bh = *(const v8h*)brow;
                v8h Bl = *(const v8h*)(brow + 64 * 72);
#pragma unroll
                for (int Mt = 0; Mt < 2; ++Mt) {
                    acc[Mt] = __builtin_amdgcn_mfma_f32_32x32x16_f16(A[Mt], Bh, acc[Mt], 0, 0, 0);
                    acc[Mt] = __builtin_amdgcn_mfma_f32_32x32x16_f16(A[Mt], Bl, acc[Mt], 0, 0, 0);
                }
                if (odut) {
                    union { uint4 u; v8h h; } bo0, bo1;
                    bo0.u = wof[kc * 2 + 0]; bo1.u = wof[kc * 2 + 1];
#pragma unroll
                    for (int Mt = 0; Mt < 2; ++Mt) {
                        oacc[Mt] = __builtin_amdgcn_mfma_f32_32x32x16_f16(A[Mt], bo0.h, oacc[Mt], 0, 0, 0);
                        oacc[Mt] = __builtin_amdgcn_mfma_f32_32x32x16_f16(A[Mt], bo1.h, oacc[Mt], 0, 0, 0);
                    }
                }
            }
            if (c < 23) {
                uint4* dst = Bs + ((c + 1) & 1) * 1152;
#pragma unroll
                for (int k2 = 0; k2 < 5; ++k2) if (k2 < npf) dst[tid + k2 * 256] = pf[k2];
            }
            __syncthreads();
        }

        // ---- hidden state update + spike bit pack ----
        uint32_t zw[2];
#pragma unroll
        for (int Mt = 0; Mt < 2; ++Mt) {
            uint32_t zzw = 0;
#pragma unroll
            for (int r = 0; r < 16; ++r) {
                float iold = iS[Mt][r];
                float vd = frn_add(vS[Mt][r], frn_mul(0.1f, frn_add(frn_sub(0.0f, vS[Mt][r]), iold)));
                bool z = frn_sub(vd, 1.0f) > 0.0f;
                vS[Mt][r] = z ? 0.0f : vd;
                float idc = frn_sub(iold, frn_mul(0.2f, iold));
                iS[Mt][r] = frn_add(idc, acc[Mt][r]);
                unsigned long long bal = __ballot(z);
                int ra = (r & 3) + ((r >> 2) << 3);
                if (lane == ra)     zzw = (uint32_t)bal;
                if (lane == ra + 4) zzw = (uint32_t)(bal >> 32);
            }
            zw[Mt] = zzw;
        }
        if (t < T - 1) {
            if (lane < 32) {
                uint32_t* bg = bitsRing + (size_t)(t + 1) * SLOT_U32;
#pragma unroll
                for (int Mt = 0; Mt < 2; ++Mt)
                    __hip_atomic_store(&bg[(size_t)(rowBase + mi * 64 + Mt * 32 + lane) * 48 + 16 + hb * 2 + nj],
                                       zw[Mt], __ATOMIC_RELAXED, __HIP_MEMORY_SCOPE_AGENT);
            }
            enc_step(t + 1);
            // preload next step's chunk-0 weight tile (overlaps exchange + barrier)
#pragma unroll
            for (int k2 = 0; k2 < 5; ++k2) if (k2 < npf) pf[k2] = wstg[tid + k2 * 256];
        }

        // ---- readout: exchange non-owned Mt tile across nj (K-halves), update io/vo/mx ----
        {
            float* X = (float*)(smem + 36864);
            const int sp = mi * 2 + (1 - nj);
#pragma unroll
            for (int r = 0; r < 16; ++r) X[(sp * 16 + r) * 64 + lane] = oacc[1 - nj][r];
            __syncthreads();
            const int sc = mi * 2 + nj;
#pragma unroll
            for (int r = 0; r < 16; ++r) {
                float s = frn_add(oacc[nj][r], X[(sc * 16 + r) * 64 + lane]);
                // voltages[t-1] = 0.9*vo + 0.1*io(t-2); then io(t-1) = 0.8*io(t-2) + S(t-1)
                vo16[r] = frn_add(vo16[r], frn_mul(0.1f, frn_sub(io16[r], vo16[r])));
                mx16[r] = fmaxf(mx16[r], vo16[r]);
                io16[r] = frn_add(frn_sub(io16[r], frn_mul(0.2f, io16[r])), s);
            }
        }
    }

    // final: voltages[T-1] = 0.9*vo + 0.1*io(T-2)
#pragma unroll
    for (int r = 0; r < 16; ++r) {
        vo16[r] = frn_add(vo16[r], frn_mul(0.1f, frn_sub(io16[r], vo16[r])));
        mx16[r] = fmaxf(mx16[r], vo16[r]);
    }

    if (ln < 16) {
#pragma unroll
        for (int r = 0; r < 16; ++r) {
            int grow = rowBase + mi * 64 + nj * 32 + (r & 3) + ((r >> 2) << 3) + (q << 2);
            outm[(size_t)grow * 256 + hb * 16 + ln] = mx16[r];
        }
    }
}

// ---------------------------------------------------------------------------
// softmax over O=256, in-place on d_out
// ---------------------------------------------------------------------------
__global__ void k_sm(float* __restrict__ o)
{
    const int lane = threadIdx.x & 63;
    const int wv4 = threadIdx.x >> 6;
    const int row = blockIdx.x * 8 + wv4 * 2 + (lane >> 5);
    const int ln = lane & 31;
    float* pr = o + (size_t)row * 256;
    float v[8];
#pragma unroll
    for (int i = 0; i < 8; ++i) v[i] = pr[ln + i * 32];
    float m = v[0];
#pragma unroll
    for (int i = 1; i < 8; ++i) m = fmaxf(m, v[i]);
#pragma unroll
    for (int off = 16; off; off >>= 1) m = fmaxf(m, __shfl_xor(m, off, 32));
    float s = 0.f;
#pragma unroll
    for (int i = 0; i < 8; ++i) { v[i] = expf(v[i] - m); s += v[i]; }
#pragma unroll
    for (int off = 16; off; off >>= 1) s += __shfl_xor(s, off, 32);
#pragma unroll
    for (int i = 0; i < 8; ++i) pr[ln + i * 32] = v[i] / s;
}

// ---------------------------------------------------------------------------
extern "C" void kernel_launch(void* const* d_in, const int* in_sizes, int n_in,
                              void* d_out, int out_size, void* d_ws, size_t ws_size,
                              hipStream_t stream)
{
    const float* x     = (const float*)d_in[0];
    const float* w_in  = (const float*)d_in[1];
    const float* w_rec = (const float*)d_in[2];
    const float* w_out = (const float*)d_in[3];
    const int*   seq   = (const int*)d_in[4];
    uint8_t* ws = (uint8_t*)d_ws;
    float* out = (float*)d_out;

    k_prep<<<1024, 256, 0, stream>>>(w_in, w_rec, w_out, ws);

    // 61952 B dynamic LDS — MUST stay under the 64 KiB per-workgroup dispatch
    // limit (requesting more silently rejects the launch -> uniform softmax).
    k_snn<<<256, 256, 61952, stream>>>(x, ws, out, seq);
    k_sm<<<256, 256, 0, stream>>>(out);
}